// Round 1
// baseline (447.225 us; speedup 1.0000x reference)
//
#include <hip/hip_runtime.h>
#include <math.h>

// Problem constants (fixed by setup_inputs).
#define CC 4
#define NN 4096
#define MM 4096
#define DD 32
#define GG 16                       // lanes per query group
#define QQ 4                        // queries per group
#define BLOCK 256
#define QPB ((BLOCK / GG) * QQ)     // 64 queries per block
#define NBLOCKS (CC * (MM / QPB))   // 256 blocks

// Insert (d, j) into sorted top-3 (d0<=d1<=d2). Strict < keeps earlier
// (lower-index) entries on ties, matching jax top_k tie-breaking within a lane.
__device__ __forceinline__ void ins3(float d, int j,
                                     float& d0, float& d1, float& d2,
                                     int& i0, int& i1, int& i2) {
    if (d < d2) {
        if (d < d1) {
            d2 = d1; i2 = i1;
            if (d < d0) { d1 = d0; i1 = i0; d0 = d; i0 = j; }
            else        { d1 = d;  i1 = j; }
        } else { d2 = d; i2 = j; }
    }
}

__global__ __launch_bounds__(BLOCK) void meshfit_topk(
    const float* __restrict__ feat,     // [CC*NN, DD]
    const float* __restrict__ verts,    // [CC, NN, 3]
    const float* __restrict__ nverts,   // [CC, MM, 3]
    float* __restrict__ out)            // [CC*MM, DD]
{
    __shared__ float2 sxy[NN];   // 32 KB
    __shared__ float  sz[NN];    // 16 KB

    const int bid  = blockIdx.x;
    const int c    = bid / (MM / QPB);
    const int tile = bid % (MM / QPB);
    const int tid  = threadIdx.x;

    // Stage class-c vertices into LDS (coalesced-ish scalar reads; tiny cost).
    const float* vc = verts + (size_t)c * NN * 3;
    for (int j = tid; j < NN; j += BLOCK) {
        sxy[j] = make_float2(vc[3 * j], vc[3 * j + 1]);
        sz[j]  = vc[3 * j + 2];
    }
    __syncthreads();

    const int g  = tid >> 4;         // group id 0..15
    const int t  = tid & 15;         // lane in group
    const int m0 = tile * QPB + g * QQ;

    // Load the group's Q query points (broadcast within group).
    const float* nvc = nverts + (size_t)c * MM * 3;
    float qx[QQ], qy[QQ], qz[QQ];
    #pragma unroll
    for (int q = 0; q < QQ; ++q) {
        qx[q] = nvc[3 * (m0 + q) + 0];
        qy[q] = nvc[3 * (m0 + q) + 1];
        qz[q] = nvc[3 * (m0 + q) + 2];
    }

    // Top-3 init with the off-block 1.0 entries (local idx = global - c*NN),
    // so the measure-zero "fewer than 3 in-block dists < 1.0" case matches ref.
    float d0[QQ], d1[QQ], d2[QQ];
    int   i0[QQ], i1[QQ], i2[QQ];
    const int offb = (c == 0) ? NN : (-c * NN);
    #pragma unroll
    for (int q = 0; q < QQ; ++q) {
        d0[q] = 1.0f; d1[q] = 1.0f; d2[q] = 1.0f;
        i0[q] = offb; i1[q] = offb + 1; i2[q] = offb + 2;
    }

    // Main scan: lane t handles candidates j = i*16 + t (conflict-free LDS:
    // 16 lanes read consecutive elements; the 4 groups broadcast same addrs).
    for (int i = 0; i < NN / GG; i += 4) {
        float2 vxy[4]; float vz[4];
        #pragma unroll
        for (int u = 0; u < 4; ++u) {
            int j = (i + u) * GG + t;
            vxy[u] = sxy[j];
            vz[u]  = sz[j];
        }
        #pragma unroll
        for (int u = 0; u < 4; ++u) {
            int j = (i + u) * GG + t;
            #pragma unroll
            for (int q = 0; q < QQ; ++q) {
                float dx = vxy[u].x - qx[q];
                float dy = vxy[u].y - qy[q];
                float dz = vz[u]    - qz[q];
                float d  = fmaf(dx, dx, fmaf(dy, dy, dz * dz));
                ins3(d, j, d0[q], d1[q], d2[q], i0[q], i1[q], i2[q]);
            }
        }
    }

    // Butterfly merge of sorted triples across the 16-lane group.
    #pragma unroll
    for (int mask = 1; mask < GG; mask <<= 1) {
        #pragma unroll
        for (int q = 0; q < QQ; ++q) {
            float e0 = __shfl_xor(d0[q], mask);
            float e1 = __shfl_xor(d1[q], mask);
            float e2 = __shfl_xor(d2[q], mask);
            int   j0 = __shfl_xor(i0[q], mask);
            int   j1 = __shfl_xor(i1[q], mask);
            int   j2 = __shfl_xor(i2[q], mask);
            ins3(e0, j0, d0[q], d1[q], d2[q], i0[q], i1[q], i2[q]);
            ins3(e1, j1, d0[q], d1[q], d2[q], i0[q], i1[q], i2[q]);
            ins3(e2, j2, d0[q], d1[q], d2[q], i0[q], i1[q], i2[q]);
        }
    }

    // Epilogue: softmax(-d) over the 3 NN, weighted feature gather.
    // All 16 lanes hold identical results; lanes split the D=32 columns.
    #pragma unroll
    for (int q = 0; q < QQ; ++q) {
        float w1 = expf(d0[q] - d1[q]);
        float w2 = expf(d0[q] - d2[q]);
        float inv = 1.0f / (1.0f + w1 + w2);
        float w0 = inv;
        w1 *= inv;
        w2 *= inv;
        const float* f0 = feat + (size_t)(i0[q] + c * NN) * DD;
        const float* f1 = feat + (size_t)(i1[q] + c * NN) * DD;
        const float* f2 = feat + (size_t)(i2[q] + c * NN) * DD;
        float* o = out + ((size_t)c * MM + (size_t)(m0 + q)) * DD;
        #pragma unroll
        for (int e = t; e < DD; e += GG) {
            o[e] = w0 * f0[e] + w1 * f1[e] + w2 * f2[e];
        }
    }
}

extern "C" void kernel_launch(void* const* d_in, const int* in_sizes, int n_in,
                              void* d_out, int out_size, void* d_ws, size_t ws_size,
                              hipStream_t stream) {
    const float* feat   = (const float*)d_in[0];   // points_feat [1, C*N, D] f32
    const float* verts  = (const float*)d_in[1];   // vertices    [C, N, 3]  f32
    const float* nverts = (const float*)d_in[2];   // new_vertices[C, M, 3]  f32
    float* outp = (float*)d_out;                   // [1, C*M, D] f32

    meshfit_topk<<<dim3(NBLOCKS), dim3(BLOCK), 0, stream>>>(feat, verts, nverts, outp);
}

// Round 2
// 90.621 us; speedup vs baseline: 4.9351x; 4.9351x over previous
//
#include <hip/hip_runtime.h>
#include <math.h>

// Problem constants (fixed by setup_inputs).
#define CC 4
#define NN 4096
#define MM 4096
#define DD 32
#define GG 32                      // lanes per query
#define BLOCK 256
#define QPB (BLOCK / GG)           // 8 queries per block
#define BPC (MM / QPB)             // 512 blocks per class
#define NBLOCKS (CC * BPC)         // 2048 blocks = 8 per CU
#define CHUNK 1024                 // vertices staged per LDS pass (12 KB)
#define NCHUNK (NN / CHUNK)        // 4

// Branchless sorted-insert of (d, j) into top-3 (d0<=d1<=d2).
// Strict < keeps earlier entries on ties (matches jax top_k tie-break).
__device__ __forceinline__ void ins3b(float d, int j,
                                      float& d0, float& d1, float& d2,
                                      int& i0, int& i1, int& i2) {
    bool l2 = d < d2, l1 = d < d1, l0 = d < d0;
    d2 = l1 ? d1 : (l2 ? d : d2);
    i2 = l1 ? i1 : (l2 ? j : i2);
    d1 = l0 ? d0 : (l1 ? d : d1);
    i1 = l0 ? i0 : (l1 ? j : i1);
    d0 = l0 ? d : d0;
    i0 = l0 ? j : i0;
}

__global__ __launch_bounds__(BLOCK, 8) void meshfit_topk(
    const float* __restrict__ feat,     // [CC*NN, DD]
    const float* __restrict__ verts,    // [CC, NN, 3]
    const float* __restrict__ nverts,   // [CC, MM, 3]
    float* __restrict__ out)            // [CC*MM, DD]
{
    __shared__ float sx[CHUNK];   // 4 KB each -> 12 KB total, 8 blocks/CU fit
    __shared__ float sy[CHUNK];
    __shared__ float sz[CHUNK];

    const int bid  = blockIdx.x;
    const int c    = bid / BPC;
    const int tile = bid % BPC;
    const int tid  = threadIdx.x;
    const int g    = tid >> 5;        // query group 0..7
    const int t    = tid & 31;        // lane within group
    const int m    = tile * QPB + g;  // query index within class

    // Query point (broadcast within the 32-lane group).
    const float* nvc = nverts + (size_t)c * MM * 3;
    const float qx = nvc[3 * m + 0];
    const float qy = nvc[3 * m + 1];
    const float qz = nvc[3 * m + 2];

    // Top-3 init with the off-block 1.0 entries (local idx = global - c*NN),
    // matching jax tie-break for the measure-zero degenerate case.
    const int offb = (c == 0) ? NN : (-c * NN);
    float d0 = 1.0f, d1 = 1.0f, d2 = 1.0f;
    int   i0 = offb, i1 = offb + 1, i2 = offb + 2;

    const float* vc = verts + (size_t)c * NN * 3;

    for (int ch = 0; ch < NCHUNK; ++ch) {
        // Stage chunk (SoA, conflict-free LDS writes: consecutive lanes ->
        // consecutive floats).
        const int cb = ch * CHUNK;
        for (int v = tid; v < CHUNK; v += BLOCK) {
            const int gv = cb + v;
            sx[v] = vc[3 * gv + 0];
            sy[v] = vc[3 * gv + 1];
            sz[v] = vc[3 * gv + 2];
        }
        __syncthreads();

        // Scan: lane t handles candidates i*32 + t. 32 lanes read consecutive
        // floats (conflict-free); wave's 2 groups broadcast same addresses.
        for (int i = 0; i < CHUNK / GG; i += 4) {
            float vx[4], vy[4], vz[4];
            #pragma unroll
            for (int u = 0; u < 4; ++u) {
                const int jj = (i + u) * GG + t;
                vx[u] = sx[jj];
                vy[u] = sy[jj];
                vz[u] = sz[jj];
            }
            #pragma unroll
            for (int u = 0; u < 4; ++u) {
                const int j = cb + (i + u) * GG + t;
                const float dx = vx[u] - qx;
                const float dy = vy[u] - qy;
                const float dz = vz[u] - qz;
                const float d  = fmaf(dx, dx, fmaf(dy, dy, dz * dz));
                ins3b(d, j, d0, d1, d2, i0, i1, i2);
            }
        }
        __syncthreads();
    }

    // Butterfly merge of sorted triples across the 32-lane group.
    #pragma unroll
    for (int mask = 1; mask < GG; mask <<= 1) {
        const float e0 = __shfl_xor(d0, mask);
        const float e1 = __shfl_xor(d1, mask);
        const float e2 = __shfl_xor(d2, mask);
        const int   j0 = __shfl_xor(i0, mask);
        const int   j1 = __shfl_xor(i1, mask);
        const int   j2 = __shfl_xor(i2, mask);
        ins3b(e0, j0, d0, d1, d2, i0, i1, i2);
        ins3b(e1, j1, d0, d1, d2, i0, i1, i2);
        ins3b(e2, j2, d0, d1, d2, i0, i1, i2);
    }

    // Epilogue: softmax(-d) over the 3 NN, weighted feature gather.
    // All 32 lanes hold identical triples; lane t handles feature column t.
    float w1 = expf(d0 - d1);
    float w2 = expf(d0 - d2);
    const float inv = 1.0f / (1.0f + w1 + w2);
    const float w0 = inv;
    w1 *= inv;
    w2 *= inv;
    const float* f0 = feat + (size_t)(i0 + c * NN) * DD;
    const float* f1 = feat + (size_t)(i1 + c * NN) * DD;
    const float* f2 = feat + (size_t)(i2 + c * NN) * DD;
    float* o = out + ((size_t)c * MM + (size_t)m) * DD;
    o[t] = w0 * f0[t] + w1 * f1[t] + w2 * f2[t];
}

extern "C" void kernel_launch(void* const* d_in, const int* in_sizes, int n_in,
                              void* d_out, int out_size, void* d_ws, size_t ws_size,
                              hipStream_t stream) {
    const float* feat   = (const float*)d_in[0];   // points_feat [1, C*N, D] f32
    const float* verts  = (const float*)d_in[1];   // vertices    [C, N, 3]  f32
    const float* nverts = (const float*)d_in[2];   // new_vertices[C, M, 3]  f32
    float* outp = (float*)d_out;                   // [1, C*M, D] f32

    meshfit_topk<<<dim3(NBLOCKS), dim3(BLOCK), 0, stream>>>(feat, verts, nverts, outp);
}